// Round 13
// baseline (697.750 us; speedup 1.0000x reference)
//
#include <hip/hip_runtime.h>
#include <math.h>

// ---------------- problem constants (from setup_inputs) ----------------
static constexpr int BATCH = 2;
static constexpr int NWIN  = 2304;
static constexpr int BN    = BATCH * NWIN;    // 4608 windows
static constexpr int S     = 64;
static constexpr int CDIM  = 256;
static constexpr int TOPK_ = 16;
static constexpr int TROWS = BN * TOPK_;      // 73728 selected rows
static constexpr int LB    = NWIN * TOPK_;    // 36864 rows per batch
static constexpr int HW    = 384;
static constexpr int KVSZ  = 8448;            // 8 heads x (32x32 KV + 32 Ksum)
static constexpr int KVB   = 384;             // partial blocks per batch
static constexpr int KVTOK = LB / KVB;        // 96 tokens per partial block

typedef unsigned short u16;
typedef unsigned long long u64;
typedef __attribute__((ext_vector_type(4))) float  f32x4;
typedef __attribute__((ext_vector_type(4))) short  bf16x4;
typedef __attribute__((ext_vector_type(8))) short  bf16x8;

__device__ inline u16 f2bf(float f) {            // RNE f32 -> bf16 bits
    unsigned u = __float_as_uint(f);
    return (u16)((u + 0x7fffu + ((u >> 16) & 1u)) >> 16);
}
__device__ inline float bf2f(u16 b) {
    return __uint_as_float(((unsigned)b) << 16);
}

__device__ inline void load_lds16(const void* g, void* l) {
    __builtin_amdgcn_global_load_lds(
        (const __attribute__((address_space(1))) unsigned int*)g,
        (__attribute__((address_space(3))) unsigned int*)l, 16, 0, 0);
}

// XCD-chunked bijective blockIdx remap (T1, m157/m204). Requires nwg%8==0.
// XCD k (= orig%8 under round-robin dispatch) gets logical chunk
// [k*cpx, (k+1)*cpx) -> logical-adjacent blocks co-locate on one XCD L2.
__device__ inline int xcd_chunk_swz(int orig, int nwg) {
    const int cpx = nwg >> 3;
    return (orig & 7) * cpx + (orig >> 3);
}

// =======================================================================
// K0: all weights -> bf16 transposed [N][K], one launch
// =======================================================================
__global__ __launch_bounds__(256) void wconv_all_k(
    const float* __restrict__ Wq, const float* __restrict__ Wk,
    const float* __restrict__ Wv, const float* __restrict__ Wm,
    const float* __restrict__ W1, const float* __restrict__ W2,
    u16* __restrict__ Wqt, u16* __restrict__ Wkt, u16* __restrict__ Wvt,
    u16* __restrict__ Wmt, u16* __restrict__ W1t, u16* __restrict__ W2t)
{
    int t = blockIdx.x * 256 + threadIdx.x;
    const float* W; u16* Wt; int Nd, Kd;
    if (t < 262144) {
        const int sel = t >> 16; t &= 65535;
        W  = (sel == 0 ? Wq  : sel == 1 ? Wk  : sel == 2 ? Wv  : Wm);
        Wt = (sel == 0 ? Wqt : sel == 1 ? Wkt : sel == 2 ? Wvt : Wmt);
        Nd = 256; Kd = 256;
    } else if (t < 524288) { W = W1; Wt = W1t; Nd = 512; Kd = 512; t -= 262144; }
    else                   { W = W2; Wt = W2t; Nd = 256; Kd = 512; t -= 524288; }
    const int k = t / Nd, n = t - k * Nd;
    Wt[(size_t)n * Kd + k] = f2bf(W[t]);
}

// =======================================================================
// K1: per-window top-k + gather. 2 windows per block, pipelined loads.
//   FROZEN: 5 structures all land 185-200us (latency-bound dep chain).
// =======================================================================
__device__ __forceinline__ void topk_process(
    const f32x4 (&v)[8], int w, bool isX, int tid, int cg, int rg,
    double2* pd, double* avgd, double* cosv, int* rk, int* slots,
    u16* __restrict__ catp, u16* __restrict__ selS, int* __restrict__ idxX)
{
    double cs[4] = {0.0, 0.0, 0.0, 0.0};
#pragma unroll
    for (int m = 0; m < 8; ++m)
#pragma unroll
        for (int q = 0; q < 4; ++q)
            cs[q] += (double)v[m][q];

    double* red = (double*)pd;           // red[rg*256 + q*64 + cg]
#pragma unroll
    for (int q = 0; q < 4; ++q)
        red[rg * 256 + q * 64 + cg] = cs[q];
    __syncthreads();

    if (tid < 256) {
        const int qq = tid & 3, cc = tid >> 2;
        double sm = 0.0;
#pragma unroll
        for (int r = 0; r < 8; ++r) sm += red[r * 256 + qq * 64 + cc];
        avgd[tid] = sm * (1.0 / 64.0);
    }
    __syncthreads();

    {
        const double a0 = avgd[cg * 4 + 0], a1 = avgd[cg * 4 + 1];
        const double a2 = avgd[cg * 4 + 2], a3 = avgd[cg * 4 + 3];
        __syncthreads();                  // red (pd) now dead, safe to overwrite
#pragma unroll
        for (int m = 0; m < 8; ++m) {
            const double x0 = (double)v[m][0], x1 = (double)v[m][1];
            const double x2 = (double)v[m][2], x3 = (double)v[m][3];
            double d = a0 * x0; d += a1 * x1; d += a2 * x2; d += a3 * x3;
            double n = x0 * x0; n += x1 * x1; n += x2 * x2; n += x3 * x3;
            d += __shfl_xor(d, 1); n += __shfl_xor(n, 1);
            d += __shfl_xor(d, 2); n += __shfl_xor(n, 2);
            if ((cg & 3) == 0)
                pd[(rg + 8 * m) * 17 + (cg >> 2)] = (double2){d, n};
        }
    }
    __syncthreads();

    {
        const int tok = tid >> 3, p = tid & 7;
        const double2 t0 = pd[tok * 17 + p * 2];
        const double2 t1 = pd[tok * 17 + p * 2 + 1];
        double sd = t0.x + t1.x, sn = t0.y + t1.y;
        sd += __shfl_xor(sd, 1); sd += __shfl_xor(sd, 2); sd += __shfl_xor(sd, 4);
        sn += __shfl_xor(sn, 1); sn += __shfl_xor(sn, 2); sn += __shfl_xor(sn, 4);
        if (p == 0) {
            double nb = sqrt(sn); if (nb < 1e-8) nb = 1e-8;
            cosv[tok] = sd / nb;           // ||avg|| dropped: window-constant
        }
    }
    __syncthreads();

    {
        const int t = tid >> 3, p = tid & 7;
        const double ct = cosv[t];
        int r = 0;
#pragma unroll
        for (int i = 0; i < 8; ++i) {
            const int j = p * 8 + i;
            const double cj = cosv[j];
            r += (cj > ct) || (cj == ct && j < t);
        }
        r += __shfl_xor(r, 1); r += __shfl_xor(r, 2); r += __shfl_xor(r, 4);
        if (p == 0) {
            rk[t] = r;
            if (r < TOPK_) slots[r] = t;
        }
    }
    __syncthreads();

    if (isX && tid < TOPK_) idxX[w * TOPK_ + tid] = slots[tid];
#pragma unroll
    for (int m = 0; m < 8; ++m) {
        const int r = rg + 8 * m;
        const int j = rk[r];                       // wave-uniform
        if (j < TOPK_) {
            u64 pk = (u64)f2bf(v[m][0]) | ((u64)f2bf(v[m][1]) << 16)
                   | ((u64)f2bf(v[m][2]) << 32) | ((u64)f2bf(v[m][3]) << 48);
            if (isX) *(u64*)&catp[((size_t)w * TOPK_ + j) * 512 + cg * 4] = pk;
            else     *(u64*)&selS[((size_t)w * TOPK_ + j) * 256 + cg * 4] = pk;
        }
    }
}

__global__ __launch_bounds__(512, 4) void topk_gather_k(
    const float* __restrict__ xin, const float* __restrict__ sin,
    u16* __restrict__ catp, u16* __restrict__ selS, int* __restrict__ idxX)
{
    __shared__ double2 pd[64 * 17];      // 17,408B; reused as red[8*256] f64
    __shared__ double  avgd[256];
    __shared__ double  cosv[64];
    __shared__ int     rk[64];
    __shared__ int     slots[16];

    const int w0   = blockIdx.x * 2;
    const bool isX = (blockIdx.y == 0);
    const int tid  = threadIdx.x;
    const int cg   = tid & 63, rg = tid >> 6;
    const float* base = isX ? xin : sin;
    const float* s0 = base + (size_t)w0 * S * CDIM;
    const float* s1 = base + (size_t)(w0 + 1) * S * CDIM;

    f32x4 vA[8], vB[8];
#pragma unroll
    for (int m = 0; m < 8; ++m)
        vA[m] = *(const f32x4*)&s0[(rg + 8 * m) * CDIM + cg * 4];
#pragma unroll
    for (int m = 0; m < 8; ++m)
        vB[m] = *(const f32x4*)&s1[(rg + 8 * m) * CDIM + cg * 4];

    topk_process(vA, w0,     isX, tid, cg, rg, pd, avgd, cosv, rk, slots,
                 catp, selS, idxX);
    __syncthreads();
    topk_process(vB, w0 + 1, isX, tid, cg, rg, pd, avgd, cosv, rk, slots,
                 catp, selS, idxX);
}

// =======================================================================
// K2 core: 8-wave bf16 MFMA GEMM, 128x256 tile, BK=32 (R6 template).
//   NB: BK=32 keeps the 64B LDS row stride -> free 2-way bank aliasing on
//   ds_read_b128; do not raise BK without a swizzle.
//   LNMODE: 0 = plain store (EPI act), 1 = LayerNorm store, 2 = LN +
//   gathered residual. LN modes need N-tile == full N (=256).
// =======================================================================
template<int EPI, int LNMODE>
__device__ inline void gemm_body8(
    const u16* __restrict__ A, int lda,
    const u16* __restrict__ Bt, int K,
    u16* __restrict__ Cout, int ldc,
    int m0, int n0,
    const float* __restrict__ gw, const float* __restrict__ gb,
    const float* __restrict__ xsrc, const int* __restrict__ idx)
{
    __shared__ u16 As[128 * 32];
    __shared__ u16 Bs[256 * 32];
    __shared__ float2 lnred[128][5];     // [row][wave-col], pad 5

    const int tid = threadIdx.x;
    const int lane = tid & 63, w = tid >> 6;
    const int wr = w >> 2, wc = w & 3;

    f32x4 acc[4][4];
#pragma unroll
    for (int i = 0; i < 4; ++i)
#pragma unroll
        for (int j = 0; j < 4; ++j)
            acc[i][j] = (f32x4){0.f, 0.f, 0.f, 0.f};

    const int rsel = lane & 15, ksel = (lane >> 4) * 8;

    for (int k0 = 0; k0 < K; k0 += 32) {
        {   // A: wave w stages chunk w
            const int e = w * 512 + lane * 8;
            const int row = e >> 5, col = e & 31;
            load_lds16(&A[(size_t)(m0 + row) * lda + k0 + col], &As[w * 512]);
        }
#pragma unroll
        for (int i = 0; i < 2; ++i) {   // B: wave w stages chunks w, w+8
            const int c = w + 8 * i;
            const int e = c * 512 + lane * 8;
            const int row = e >> 5, col = e & 31;
            load_lds16(&Bt[(size_t)(n0 + row) * K + k0 + col], &Bs[c * 512]);
        }
        __syncthreads();

        bf16x8 af[4], bfr[4];
#pragma unroll
        for (int i = 0; i < 4; ++i)
            af[i] = *(const bf16x8*)&As[(wr * 64 + i * 16 + rsel) * 32 + ksel];
#pragma unroll
        for (int j = 0; j < 4; ++j)
            bfr[j] = *(const bf16x8*)&Bs[(wc * 64 + j * 16 + rsel) * 32 + ksel];
#pragma unroll
        for (int i = 0; i < 4; ++i)
#pragma unroll
            for (int j = 0; j < 4; ++j)
                acc[i][j] = __builtin_amdgcn_mfma_f32_16x16x32_bf16(
                    af[i], bfr[j], acc[i][j], 0, 0, 0);
        __syncthreads();
    }

    const int g = lane >> 4, ccol = lane & 15;

    if (LNMODE == 0) {
#pragma unroll
        for (int i = 0; i < 4; ++i)
#pragma unroll
            for (int j = 0; j < 4; ++j)
#pragma unroll
                for (int r = 0; r < 4; ++r) {
                    float v = acc[i][j][r];
                    if (EPI == 1) v = (v > 0.f) ? (v + 1.f) : __expf(v);  // elu+1
                    if (EPI == 2) v = (v > 0.f) ? v : 0.f;
                    Cout[(size_t)(m0 + wr * 64 + i * 16 + g * 4 + r) * ldc
                         + (n0 + wc * 64 + j * 16 + ccol)] = f2bf(v);
                }
    } else {
#pragma unroll
        for (int i = 0; i < 4; ++i)
#pragma unroll
            for (int r = 0; r < 4; ++r) {
                float s = 0.f, q = 0.f;
#pragma unroll
                for (int j = 0; j < 4; ++j) {
                    const float v = acc[i][j][r];
                    s += v; q += v * v;
                }
#pragma unroll
                for (int m = 1; m < 16; m <<= 1) {
                    s += __shfl_xor(s, m); q += __shfl_xor(q, m);
                }
                if (ccol == 0)
                    lnred[wr * 64 + i * 16 + g * 4 + r][wc] = (float2){s, q};
            }
        __syncthreads();

#pragma unroll
        for (int i = 0; i < 4; ++i)
#pragma unroll
            for (int r = 0; r < 4; ++r) {
                const int lrow = wr * 64 + i * 16 + g * 4 + r;
                const float2 p0 = lnred[lrow][0], p1 = lnred[lrow][1];
                const float2 p2 = lnred[lrow][2], p3 = lnred[lrow][3];
                const float Sm = p0.x + p1.x + p2.x + p3.x;
                const float Qm = p0.y + p1.y + p2.y + p3.y;
                const float mean = Sm * (1.f / 256.f);
                const float rstd = rsqrtf(Qm * (1.f / 256.f) - mean * mean + 1e-5f);
                const int row = m0 + lrow;
                const float* xr = nullptr;
                if (LNMODE == 2)
                    xr = xsrc + ((size_t)(row >> 4) * 64 + idx[row]) * 256;
#pragma unroll
                for (int j = 0; j < 4; ++j) {
                    const int col = wc * 64 + j * 16 + ccol;
                    float o = (acc[i][j][r] - mean) * rstd * gw[col] + gb[col];
                    if (LNMODE == 2) o += xr[col];
                    Cout[(size_t)row * ldc + col] = f2bf(o);
                }
            }
    }
}

template<int EPI, int LNMODE>
__global__ __launch_bounds__(512) void gemm8_k(
    const u16* __restrict__ A, int lda,
    const u16* __restrict__ Bt, int K,
    u16* __restrict__ Cout, int ldc,
    const float* __restrict__ gw, const float* __restrict__ gb,
    const float* __restrict__ xsrc, const int* __restrict__ idx)
{
    gemm_body8<EPI, LNMODE>(A, lda, Bt, K, Cout, ldc,
                            blockIdx.y * 128, blockIdx.x * 256,
                            gw, gb, xsrc, idx);
}

// W1 GEMM, XCD-swizzled 1-D grid (1152): logical = y*2 + x so the two
// N-tiles sharing an A-panel are XCD-co-located and time-adjacent.
__global__ __launch_bounds__(512) void gemm_w1_k(
    const u16* __restrict__ A, const u16* __restrict__ Bt,
    u16* __restrict__ Cout)
{
    const int lg = xcd_chunk_swz(blockIdx.x, (TROWS / 128) * 2);
    const int y = lg >> 1, xn = lg & 1;
    gemm_body8<2, 0>(A, 512, Bt, 512, Cout, 512, y * 128, xn * 256,
                     nullptr, nullptr, nullptr, nullptr);
}

// fused Q/K/V, XCD-swizzled 1-D grid (1728): logical = y*3 + z so the
// K-GEMM and V-GEMM blocks sharing a selS A-panel are co-located.
__global__ __launch_bounds__(512) void gemm_qkv_k(
    const u16* __restrict__ catA, const u16* __restrict__ selS,
    const u16* __restrict__ Wqt, const u16* __restrict__ Wkt,
    const u16* __restrict__ Wvt,
    u16* __restrict__ Qb, u16* __restrict__ Kb, u16* __restrict__ Vb)
{
    const int lg = xcd_chunk_swz(blockIdx.x, (TROWS / 128) * 3);
    const int y = lg / 3, z = lg % 3;
    if (z == 0)
        gemm_body8<1, 0>(catA, 512, Wqt, 256, Qb, 256, y * 128, 0,
                         nullptr, nullptr, nullptr, nullptr);
    else if (z == 1)
        gemm_body8<1, 0>(selS, 256, Wkt, 256, Kb, 256, y * 128, 0,
                         nullptr, nullptr, nullptr, nullptr);
    else
        gemm_body8<0, 0>(selS, 256, Wvt, 256, Vb, 256, y * 128, 0,
                         nullptr, nullptr, nullptr, nullptr);
}

// =======================================================================
// K3: KV/Ksum block partials (bf16 K,V). 768 blocks, 96 tokens each.
// =======================================================================
__global__ __launch_bounds__(256) void kv_part_k(
    const u16* __restrict__ Kb, const u16* __restrict__ Vb,
    float* __restrict__ part)
{
    __shared__ float Kt[16][257];
    __shared__ float Vt[16][257];

    const int bk = blockIdx.x;
    const int batch = bk / KVB, slot = bk % KVB;
    const size_t r0 = (size_t)batch * LB + (size_t)slot * KVTOK;
    const int h = threadIdx.x >> 5, e = threadIdx.x & 31;
    const int sr = threadIdx.x >> 4, sc = (threadIdx.x & 15) * 4;  // staging map

    float acc[32] = {};
    float ks = 0.f;

    for (int tile = 0; tile < KVTOK / 16; ++tile) {
        const size_t rb = r0 + tile * 16;
#pragma unroll
        for (int k = 0; k < 4; ++k) {
            const int col = sc + 64 * k;
            const bf16x4 kk = *(const bf16x4*)&Kb[(rb + sr) * 256 + col];
            const bf16x4 vv4 = *(const bf16x4*)&Vb[(rb + sr) * 256 + col];
            Kt[sr][col + 0] = bf2f((u16)kk[0]); Kt[sr][col + 1] = bf2f((u16)kk[1]);
            Kt[sr][col + 2] = bf2f((u16)kk[2]); Kt[sr][col + 3] = bf2f((u16)kk[3]);
            Vt[sr][col + 0] = bf2f((u16)vv4[0]); Vt[sr][col + 1] = bf2f((u16)vv4[1]);
            Vt[sr][col + 2] = bf2f((u16)vv4[2]); Vt[sr][col + 3] = bf2f((u16)vv4[3]);
        }
        __syncthreads();
        for (int s = 0; s < 16; ++s) {
            const float vv = Vt[s][(h << 5) + e];
            ks += Kt[s][(h << 5) + e];
#pragma unroll
            for (int d = 0; d < 32; ++d)
                acc[d] += Kt[s][(h << 5) + d] * vv;
        }
        __syncthreads();
    }

    float* pb = part + (size_t)bk * KVSZ;
    for (int d = 0; d < 32; ++d)
        pb[((h << 5) + d) * 32 + e] = acc[d];
    pb[8192 + threadIdx.x] = ks;
}

// K4: reduce KVB partials per batch -> KVfin[2][KVSZ]
__global__ __launch_bounds__(256) void kv_reduce_k(
    const float* __restrict__ part, float* __restrict__ fin)
{
    __shared__ float r2[4][64];
    const int chunk = blockIdx.x;                 // 264 = 2 * (8448/64)
    const int b = chunk / (KVSZ / 64);
    const int i0 = (chunk % (KVSZ / 64)) * 64;
    const int il = threadIdx.x & 63, pg = threadIdx.x >> 6;

    float s = 0.f;
    for (int p = pg; p < KVB; p += 4)
        s += part[(size_t)(b * KVB + p) * KVSZ + i0 + il];
    r2[pg][il] = s;
    __syncthreads();
    if (threadIdx.x < 64)
        fin[(size_t)b * KVSZ + i0 + threadIdx.x] =
            r2[0][threadIdx.x] + r2[1][threadIdx.x] +
            r2[2][threadIdx.x] + r2[3][threadIdx.x];
}

// =======================================================================
// K5: attention apply (bf16 Q) -> bf16 msg. Vectorized staging.
// =======================================================================
__global__ __launch_bounds__(256) void attn_apply_k(
    const u16* __restrict__ Q, const float* __restrict__ KV,
    u16* __restrict__ outp)
{
    __shared__ float kvs[8192];
    __shared__ float kss[256];
    __shared__ float qs[8][258];

    const int tid = threadIdx.x;
    const int t0 = blockIdx.x * 64;
    const int batch = t0 / LB;
    const float* kvb = KV + (size_t)batch * KVSZ;
    for (int i = tid * 4; i < 8192; i += 1024)
        *(f32x4*)&kvs[i] = *(const f32x4*)&kvb[i];
    kss[tid] = kvb[8192 + tid];
    const int h = tid >> 5, e = tid & 31;
    const int qr = tid >> 5, qc = (tid & 31) * 8;     // staging map
    __syncthreads();

    for (int o = 0; o < 64; o += 8) {
        __syncthreads();
        const bf16x8 qv = *(const bf16x8*)&Q[(size_t)(t0 + o + qr) * 256 + qc];
#pragma unroll
        for (int q = 0; q < 8; ++q) qs[qr][qc + q] = bf2f((u16)qv[q]);
        __syncthreads();
        for (int tt = 0; tt < 8; ++tt) {
            const float* qh = &qs[tt][h << 5];
            float zq = 0.f, res = 0.f;
#pragma unroll
            for (int d = 0; d < 32; ++d) {
                const float qd = qh[d];
                zq  += qd * kss[(h << 5) + d];
                res += qd * kvs[((h << 5) + d) * 32 + e];
            }
            outp[(size_t)(t0 + o + tt) * 256 + tid] = f2bf(res / (zq + 1e-6f));
        }
    }
}

// =======================================================================
// K7: combined = x + scatter(outsel) fused with window_reverse -> NCHW
// =======================================================================
__global__ __launch_bounds__(256) void combine_reverse_k(
    const float* __restrict__ xin, const int* __restrict__ idxX,
    const u16* __restrict__ outsel, float* __restrict__ outp)
{
    __shared__ float tile[128 * 33];
    __shared__ int   sidx[32];

    const int p  = blockIdx.x;
    const int c0 = blockIdx.y * 32;
    const int b  = p / 1152;
    const int rem = p % 1152;
    const int wy  = rem / 24, wxp = rem % 24;
    const int w0  = b * NWIN + wy * 48 + wxp * 2;
    const int tid = threadIdx.x;

    if (tid < 32) sidx[tid] = idxX[(w0 + (tid >> 4)) * TOPK_ + (tid & 15)];

    {
        const int r = tid >> 1, half = tid & 1;
        const int wl = r >> 6, t = r & 63;
        const float* srcp = xin + ((size_t)(w0 + wl) * 64 + t) * 256 + c0 + half * 16;
        const float4 v0 = ((const float4*)srcp)[0];
        const float4 v1 = ((const float4*)srcp)[1];
        const float4 v2 = ((const float4*)srcp)[2];
        const float4 v3 = ((const float4*)srcp)[3];
        float* dst = &tile[r * 33 + half * 16];
        dst[0] = v0.x; dst[1] = v0.y; dst[2]  = v0.z; dst[3]  = v0.w;
        dst[4] = v1.x; dst[5] = v1.y; dst[6]  = v1.z; dst[7]  = v1.w;
        dst[8] = v2.x; dst[9] = v2.y; dst[10] = v2.z; dst[11] = v2.w;
        dst[12] = v3.x; dst[13] = v3.y; dst[14] = v3.z; dst[15] = v3.w;
    }
    __syncthreads();

    for (int it = 0; it < 4; ++it) {
        const int rid = it * 8 + (tid >> 5);
        const int cc  = tid & 31;
        const int wl  = rid >> 4, j = rid & 15;
        const int t   = sidx[rid];
        tile[((wl << 6) + t) * 33 + cc] +=
            bf2f(outsel[((size_t)(w0 + wl) * TOPK_ + j) * 256 + c0 + cc]);
    }
    __syncthreads();

    const int chalf = tid >> 7;
    const int pix = tid & 127;
    const int dy = pix >> 4, x16 = pix & 15;
    const int wl = x16 >> 3, dx = x16 & 7;
    const int rr = (wl << 6) + dy * 8 + dx;
    const size_t obase = (((size_t)b * 256 + c0 + chalf) * HW + (wy * 8 + dy)) * HW
                       + wxp * 16 + x16;
    for (int cc = 0; cc < 32; cc += 2)
        outp[obase + (size_t)cc * (HW * HW)] = tile[rr * 33 + cc + chalf];
}

// =======================================================================
extern "C" void kernel_launch(void* const* d_in, const int* in_sizes, int n_in,
                              void* d_out, int out_size, void* d_ws, size_t ws_size,
                              hipStream_t stream)
{
    const float* x   = (const float*)d_in[0];
    const float* s   = (const float*)d_in[1];
    const float* Wq  = (const float*)d_in[2];
    const float* Wk  = (const float*)d_in[3];
    const float* Wv  = (const float*)d_in[4];
    const float* Wm  = (const float*)d_in[5];
    const float* W1  = (const float*)d_in[6];
    const float* W2  = (const float*)d_in[7];
    const float* n1w = (const float*)d_in[8];
    const float* n1b = (const float*)d_in[9];
    const float* n2w = (const float*)d_in[10];
    const float* n2b = (const float*)d_in[11];
    float* out = (float*)d_out;

    // ---- workspace layout (bytes) ----
    char* ws = (char*)d_ws;
    int*   idxX   = (int*)ws;                          //    294,912
    float* KVpart = (float*)(ws + 294912);             // 25,952,256
    float* KVfin  = (float*)(ws + 26247168);           //     67,584
    u16*   Wqt    = (u16*)(ws + 26314752);             //    131,072
    u16*   Wkt    = (u16*)(ws + 26445824);             //    131,072
    u16*   Wvt    = (u16*)(ws + 26576896);             //    131,072
    u16*   Wmt    = (u16*)(ws + 26707968);             //    131,072
    u16*   W1t    = (u16*)(ws + 26839040);             //    524,288
    u16*   W2t    = (u16*)(ws + 27363328);             //    262,144
    u16*   Qb     = (u16*)(ws + 27625472);             // 37,748,736
    u16*   Kb     = (u16*)(ws + 65374208);             // 37,748,736
    u16*   Vb     = (u16*)(ws + 103122944);            // 37,748,736
    u16*   osel   = (u16*)(ws + 140871680);            // 37,748,736  outsel (bf16)

    // ---- bf16 intermediates in d_out (dead before final combine) ----
    u16* catA  = (u16*)d_out;                          // [T][512] sel1 | LN1(merge)
    u16* selSb = (u16*)((char*)d_out + 75497472);      // [T][256]
    u16* msgA  = (u16*)((char*)d_out + 113246208);     // [T][256]
    u16* Hb    = (u16*)((char*)d_out + 150994944);     // [T][512]

    // 0) weights -> bf16 transposed [N][K]
    wconv_all_k<<<dim3(2560), 256, 0, stream>>>(Wq, Wk, Wv, Wm, W1, W2,
                                                Wqt, Wkt, Wvt, Wmt, W1t, W2t);

    // 1) top-k + gather (2 windows per block, pipelined loads)
    topk_gather_k<<<dim3(BN / 2, 2), 512, 0, stream>>>(x, s, catA, selSb, idxX);

    // 2) fused Q/K/V GEMMs (128x256 tiles, XCD-swizzled grid)
    gemm_qkv_k<<<dim3((TROWS / 128) * 3), 512, 0, stream>>>(
        catA, selSb, Wqt, Wkt, Wvt, Qb, Kb, Vb);

    // 3) KV / Ksum aggregation (deterministic two-stage)
    kv_part_k<<<dim3(2 * KVB), 256, 0, stream>>>(Kb, Vb, KVpart);
    kv_reduce_k<<<dim3(2 * (KVSZ / 64)), 256, 0, stream>>>(KVpart, KVfin);

    // 4) attention apply -> bf16 msg
    attn_apply_k<<<dim3(TROWS / 64), 256, 0, stream>>>(Qb, KVfin, msgA);

    // 5) merge GEMM + fused LN1 -> catA right half (bf16)
    gemm8_k<0, 1><<<dim3(1, 576), 512, 0, stream>>>(
        msgA, 256, Wmt, 256, catA + 256, 512, n1w, n1b, nullptr, nullptr);

    // 6) H = relu(cat@W1) (bf16, XCD-swizzled grid: A-panel pairs co-located)
    gemm_w1_k<<<dim3((TROWS / 128) * 2), 512, 0, stream>>>(catA, W1t, Hb);

    // 7) W2 GEMM + fused LN2 + residual gather -> osel (bf16)
    gemm8_k<0, 2><<<dim3(1, 576), 512, 0, stream>>>(
        Hb, 512, W2t, 512, osel, 256, n2w, n2b, x, idxX);

    // 8) combined = x + scatter(outsel); window_reverse -> NCHW out
    combine_reverse_k<<<dim3(BN / 2, 8), 256, 0, stream>>>(x, idxX, osel, out);
}

// Round 14
// 680.607 us; speedup vs baseline: 1.0252x; 1.0252x over previous
//
#include <hip/hip_runtime.h>
#include <math.h>

// ---------------- problem constants (from setup_inputs) ----------------
static constexpr int BATCH = 2;
static constexpr int NWIN  = 2304;
static constexpr int BN    = BATCH * NWIN;    // 4608 windows
static constexpr int S     = 64;
static constexpr int CDIM  = 256;
static constexpr int TOPK_ = 16;
static constexpr int TROWS = BN * TOPK_;      // 73728 selected rows
static constexpr int LB    = NWIN * TOPK_;    // 36864 rows per batch
static constexpr int HW    = 384;
static constexpr int KVSZ  = 8448;            // 8 heads x (32x32 KV + 32 Ksum)
static constexpr int KVB   = 384;             // partial blocks per batch
static constexpr int KVTOK = LB / KVB;        // 96 tokens per partial block

typedef unsigned short u16;
typedef unsigned long long u64;
typedef __attribute__((ext_vector_type(4))) float  f32x4;
typedef __attribute__((ext_vector_type(8))) short  bf16x8;

__device__ inline u16 f2bf(float f) {            // RNE f32 -> bf16 bits
    unsigned u = __float_as_uint(f);
    return (u16)((u + 0x7fffu + ((u >> 16) & 1u)) >> 16);
}
__device__ inline float bf2f(u16 b) {
    return __uint_as_float(((unsigned)b) << 16);
}

__device__ inline void load_lds16(const void* g, void* l) {
    __builtin_amdgcn_global_load_lds(
        (const __attribute__((address_space(1))) unsigned int*)g,
        (__attribute__((address_space(3))) unsigned int*)l, 16, 0, 0);
}

// =======================================================================
// K0: all weights -> bf16 transposed [N][K], one launch
// =======================================================================
__global__ __launch_bounds__(256) void wconv_all_k(
    const float* __restrict__ Wq, const float* __restrict__ Wk,
    const float* __restrict__ Wv, const float* __restrict__ Wm,
    const float* __restrict__ W1, const float* __restrict__ W2,
    u16* __restrict__ Wqt, u16* __restrict__ Wkt, u16* __restrict__ Wvt,
    u16* __restrict__ Wmt, u16* __restrict__ W1t, u16* __restrict__ W2t)
{
    int t = blockIdx.x * 256 + threadIdx.x;
    const float* W; u16* Wt; int Nd, Kd;
    if (t < 262144) {
        const int sel = t >> 16; t &= 65535;
        W  = (sel == 0 ? Wq  : sel == 1 ? Wk  : sel == 2 ? Wv  : Wm);
        Wt = (sel == 0 ? Wqt : sel == 1 ? Wkt : sel == 2 ? Wvt : Wmt);
        Nd = 256; Kd = 256;
    } else if (t < 524288) { W = W1; Wt = W1t; Nd = 512; Kd = 512; t -= 262144; }
    else                   { W = W2; Wt = W2t; Nd = 256; Kd = 512; t -= 524288; }
    const int k = t / Nd, n = t - k * Nd;
    Wt[(size_t)n * Kd + k] = f2bf(W[t]);
}

// =======================================================================
// K1: per-window top-k + gather, register-resident window (R5 numerics;
//   rank phase parallelized across all waves). FROZEN at ~190us.
// =======================================================================
__global__ __launch_bounds__(512) void topk_gather_k(
    const float* __restrict__ xin, const float* __restrict__ sin,
    u16* __restrict__ catp, u16* __restrict__ selS, int* __restrict__ idxX)
{
    __shared__ double2 pd[64 * 17];      // 17,408B; reused as red[8*256] f64
    __shared__ double  avgd[256];
    __shared__ double  cosv[64];
    __shared__ int     rk[64];
    __shared__ int     slots[16];

    const int w    = blockIdx.x;
    const bool isX = (blockIdx.y == 0);
    const int tid  = threadIdx.x;
    const int cg   = tid & 63, rg = tid >> 6;
    const float* src = (isX ? xin : sin) + (size_t)w * S * CDIM;

    f32x4 v[8];
#pragma unroll
    for (int m = 0; m < 8; ++m)
        v[m] = *(const f32x4*)&src[(rg + 8 * m) * CDIM + cg * 4];

    double cs[4] = {0.0, 0.0, 0.0, 0.0};
#pragma unroll
    for (int m = 0; m < 8; ++m)
#pragma unroll
        for (int q = 0; q < 4; ++q)
            cs[q] += (double)v[m][q];

    double* red = (double*)pd;           // red[rg*256 + q*64 + cg]
#pragma unroll
    for (int q = 0; q < 4; ++q)
        red[rg * 256 + q * 64 + cg] = cs[q];
    __syncthreads();

    if (tid < 256) {
        const int qq = tid & 3, cc = tid >> 2;
        double sm = 0.0;
#pragma unroll
        for (int r = 0; r < 8; ++r) sm += red[r * 256 + qq * 64 + cc];
        avgd[tid] = sm * (1.0 / 64.0);
    }
    __syncthreads();

    {
        const double a0 = avgd[cg * 4 + 0], a1 = avgd[cg * 4 + 1];
        const double a2 = avgd[cg * 4 + 2], a3 = avgd[cg * 4 + 3];
        __syncthreads();
#pragma unroll
        for (int m = 0; m < 8; ++m) {
            const double x0 = (double)v[m][0], x1 = (double)v[m][1];
            const double x2 = (double)v[m][2], x3 = (double)v[m][3];
            double d = a0 * x0; d += a1 * x1; d += a2 * x2; d += a3 * x3;
            double n = x0 * x0; n += x1 * x1; n += x2 * x2; n += x3 * x3;
            d += __shfl_xor(d, 1); n += __shfl_xor(n, 1);
            d += __shfl_xor(d, 2); n += __shfl_xor(n, 2);
            if ((cg & 3) == 0)
                pd[(rg + 8 * m) * 17 + (cg >> 2)] = (double2){d, n};
        }
    }
    __syncthreads();

    {
        const int tok = tid >> 3, p = tid & 7;
        const double2 t0 = pd[tok * 17 + p * 2];
        const double2 t1 = pd[tok * 17 + p * 2 + 1];
        double sd = t0.x + t1.x, sn = t0.y + t1.y;
        sd += __shfl_xor(sd, 1); sd += __shfl_xor(sd, 2); sd += __shfl_xor(sd, 4);
        sn += __shfl_xor(sn, 1); sn += __shfl_xor(sn, 2); sn += __shfl_xor(sn, 4);
        if (p == 0) {
            double nb = sqrt(sn); if (nb < 1e-8) nb = 1e-8;
            cosv[tok] = sd / nb;           // ||avg|| dropped: window-constant
        }
    }
    __syncthreads();

    // stable descending rank, parallel over all waves (t = tid>>3, slice p)
    {
        const int t = tid >> 3, p = tid & 7;
        const double ct = cosv[t];
        int r = 0;
#pragma unroll
        for (int i = 0; i < 8; ++i) {
            const int j = p * 8 + i;
            const double cj = cosv[j];
            r += (cj > ct) || (cj == ct && j < t);
        }
        r += __shfl_xor(r, 1); r += __shfl_xor(r, 2); r += __shfl_xor(r, 4);
        if (p == 0) {
            rk[t] = r;
            if (r < TOPK_) slots[r] = t;
        }
    }
    __syncthreads();

    if (isX && tid < TOPK_) idxX[w * TOPK_ + tid] = slots[tid];
#pragma unroll
    for (int m = 0; m < 8; ++m) {
        const int r = rg + 8 * m;
        const int j = rk[r];                       // wave-uniform
        if (j < TOPK_) {
            u64 pk = (u64)f2bf(v[m][0]) | ((u64)f2bf(v[m][1]) << 16)
                   | ((u64)f2bf(v[m][2]) << 32) | ((u64)f2bf(v[m][3]) << 48);
            if (isX) *(u64*)&catp[((size_t)w * TOPK_ + j) * 512 + cg * 4] = pk;
            else     *(u64*)&selS[((size_t)w * TOPK_ + j) * 256 + cg * 4] = pk;
        }
    }
}

// =======================================================================
// K2 core: 8-wave bf16 MFMA GEMM, 128x256 tile, BK=32 (R6 template).
//   LNMODE: 0 = plain store (EPI act), 1 = LayerNorm store, 2 = LN +
//   gathered residual. LN modes need N-tile == full N (=256).
// =======================================================================
template<int EPI, int LNMODE>
__device__ inline void gemm_body8(
    const u16* __restrict__ A, int lda,
    const u16* __restrict__ Bt, int K,
    u16* __restrict__ Cout, int ldc,
    int m0, int n0,
    const float* __restrict__ gw, const float* __restrict__ gb,
    const float* __restrict__ xsrc, const int* __restrict__ idx)
{
    __shared__ u16 As[128 * 32];
    __shared__ u16 Bs[256 * 32];
    __shared__ float2 lnred[128][5];     // [row][wave-col], pad 5

    const int tid = threadIdx.x;
    const int lane = tid & 63, w = tid >> 6;
    const int wr = w >> 2, wc = w & 3;

    f32x4 acc[4][4];
#pragma unroll
    for (int i = 0; i < 4; ++i)
#pragma unroll
        for (int j = 0; j < 4; ++j)
            acc[i][j] = (f32x4){0.f, 0.f, 0.f, 0.f};

    const int rsel = lane & 15, ksel = (lane >> 4) * 8;

    for (int k0 = 0; k0 < K; k0 += 32) {
        {   // A: wave w stages chunk w
            const int e = w * 512 + lane * 8;
            const int row = e >> 5, col = e & 31;
            load_lds16(&A[(size_t)(m0 + row) * lda + k0 + col], &As[w * 512]);
        }
#pragma unroll
        for (int i = 0; i < 2; ++i) {   // B: wave w stages chunks w, w+8
            const int c = w + 8 * i;
            const int e = c * 512 + lane * 8;
            const int row = e >> 5, col = e & 31;
            load_lds16(&Bt[(size_t)(n0 + row) * K + k0 + col], &Bs[c * 512]);
        }
        __syncthreads();

        bf16x8 af[4], bfr[4];
#pragma unroll
        for (int i = 0; i < 4; ++i)
            af[i] = *(const bf16x8*)&As[(wr * 64 + i * 16 + rsel) * 32 + ksel];
#pragma unroll
        for (int j = 0; j < 4; ++j)
            bfr[j] = *(const bf16x8*)&Bs[(wc * 64 + j * 16 + rsel) * 32 + ksel];
#pragma unroll
        for (int i = 0; i < 4; ++i)
#pragma unroll
            for (int j = 0; j < 4; ++j)
                acc[i][j] = __builtin_amdgcn_mfma_f32_16x16x32_bf16(
                    af[i], bfr[j], acc[i][j], 0, 0, 0);
        __syncthreads();
    }

    const int g = lane >> 4, ccol = lane & 15;

    if (LNMODE == 0) {
#pragma unroll
        for (int i = 0; i < 4; ++i)
#pragma unroll
            for (int j = 0; j < 4; ++j)
#pragma unroll
                for (int r = 0; r < 4; ++r) {
                    float v = acc[i][j][r];
                    if (EPI == 1) v = (v > 0.f) ? (v + 1.f) : __expf(v);  // elu+1
                    if (EPI == 2) v = (v > 0.f) ? v : 0.f;
                    Cout[(size_t)(m0 + wr * 64 + i * 16 + g * 4 + r) * ldc
                         + (n0 + wc * 64 + j * 16 + ccol)] = f2bf(v);
                }
    } else {
#pragma unroll
        for (int i = 0; i < 4; ++i)
#pragma unroll
            for (int r = 0; r < 4; ++r) {
                float s = 0.f, q = 0.f;
#pragma unroll
                for (int j = 0; j < 4; ++j) {
                    const float v = acc[i][j][r];
                    s += v; q += v * v;
                }
#pragma unroll
                for (int m = 1; m < 16; m <<= 1) {
                    s += __shfl_xor(s, m); q += __shfl_xor(q, m);
                }
                if (ccol == 0)
                    lnred[wr * 64 + i * 16 + g * 4 + r][wc] = (float2){s, q};
            }
        __syncthreads();

#pragma unroll
        for (int i = 0; i < 4; ++i)
#pragma unroll
            for (int r = 0; r < 4; ++r) {
                const int lrow = wr * 64 + i * 16 + g * 4 + r;
                const float2 p0 = lnred[lrow][0], p1 = lnred[lrow][1];
                const float2 p2 = lnred[lrow][2], p3 = lnred[lrow][3];
                const float Sm = p0.x + p1.x + p2.x + p3.x;
                const float Qm = p0.y + p1.y + p2.y + p3.y;
                const float mean = Sm * (1.f / 256.f);
                const float rstd = rsqrtf(Qm * (1.f / 256.f) - mean * mean + 1e-5f);
                const int row = m0 + lrow;
                const float* xr = nullptr;
                if (LNMODE == 2)
                    xr = xsrc + ((size_t)(row >> 4) * 64 + idx[row]) * 256;
#pragma unroll
                for (int j = 0; j < 4; ++j) {
                    const int col = wc * 64 + j * 16 + ccol;
                    float o = (acc[i][j][r] - mean) * rstd * gw[col] + gb[col];
                    if (LNMODE == 2) o += xr[col];
                    Cout[(size_t)row * ldc + col] = f2bf(o);
                }
            }
    }
}

template<int EPI, int LNMODE>
__global__ __launch_bounds__(512) void gemm8_k(
    const u16* __restrict__ A, int lda,
    const u16* __restrict__ Bt, int K,
    u16* __restrict__ Cout, int ldc,
    const float* __restrict__ gw, const float* __restrict__ gb,
    const float* __restrict__ xsrc, const int* __restrict__ idx)
{
    gemm_body8<EPI, LNMODE>(A, lda, Bt, K, Cout, ldc,
                            blockIdx.y * 128, blockIdx.x * 256,
                            gw, gb, xsrc, idx);
}

// fused Q/K/V: z selects operand set; Q,K use elu+1, V none
__global__ __launch_bounds__(512) void gemm_qkv_k(
    const u16* __restrict__ catA, const u16* __restrict__ selS,
    const u16* __restrict__ Wqt, const u16* __restrict__ Wkt,
    const u16* __restrict__ Wvt,
    u16* __restrict__ Qb, u16* __restrict__ Kb, u16* __restrict__ Vb)
{
    const int z = blockIdx.z;
    if (z == 0)
        gemm_body8<1, 0>(catA, 512, Wqt, 256, Qb, 256, blockIdx.y * 128, 0,
                         nullptr, nullptr, nullptr, nullptr);
    else if (z == 1)
        gemm_body8<1, 0>(selS, 256, Wkt, 256, Kb, 256, blockIdx.y * 128, 0,
                         nullptr, nullptr, nullptr, nullptr);
    else
        gemm_body8<0, 0>(selS, 256, Wvt, 256, Vb, 256, blockIdx.y * 128, 0,
                         nullptr, nullptr, nullptr, nullptr);
}

// =======================================================================
// K3: KV/Ksum block partials (bf16 K,V). 768 blocks, 96 tokens each.
// =======================================================================
__global__ __launch_bounds__(256) void kv_part_k(
    const u16* __restrict__ Kb, const u16* __restrict__ Vb,
    float* __restrict__ part)
{
    __shared__ float Kt[16][256];
    __shared__ float Vt[16][256];

    const int bk = blockIdx.x;
    const int batch = bk / KVB, slot = bk % KVB;
    const size_t r0 = (size_t)batch * LB + (size_t)slot * KVTOK;
    const int h = threadIdx.x >> 5, e = threadIdx.x & 31;

    float acc[32] = {};
    float ks = 0.f;

    for (int tile = 0; tile < KVTOK / 16; ++tile) {
        const size_t rb = r0 + tile * 16;
        for (int i = 0; i < 16; ++i) {
            Kt[i][threadIdx.x] = bf2f(Kb[(rb + i) * 256 + threadIdx.x]);
            Vt[i][threadIdx.x] = bf2f(Vb[(rb + i) * 256 + threadIdx.x]);
        }
        __syncthreads();
        for (int s = 0; s < 16; ++s) {
            const float vv = Vt[s][(h << 5) + e];
            ks += Kt[s][(h << 5) + e];
#pragma unroll
            for (int d = 0; d < 32; ++d)
                acc[d] += Kt[s][(h << 5) + d] * vv;
        }
        __syncthreads();
    }

    float* pb = part + (size_t)bk * KVSZ;
    for (int d = 0; d < 32; ++d)
        pb[((h << 5) + d) * 32 + e] = acc[d];
    pb[8192 + threadIdx.x] = ks;
}

// K4: reduce KVB partials per batch -> KVfin[2][KVSZ]
__global__ __launch_bounds__(256) void kv_reduce_k(
    const float* __restrict__ part, float* __restrict__ fin)
{
    __shared__ float r2[4][64];
    const int chunk = blockIdx.x;                 // 264 = 2 * (8448/64)
    const int b = chunk / (KVSZ / 64);
    const int i0 = (chunk % (KVSZ / 64)) * 64;
    const int il = threadIdx.x & 63, pg = threadIdx.x >> 6;

    float s = 0.f;
    for (int p = pg; p < KVB; p += 4)
        s += part[(size_t)(b * KVB + p) * KVSZ + i0 + il];
    r2[pg][il] = s;
    __syncthreads();
    if (threadIdx.x < 64)
        fin[(size_t)b * KVSZ + i0 + threadIdx.x] =
            r2[0][threadIdx.x] + r2[1][threadIdx.x] +
            r2[2][threadIdx.x] + r2[3][threadIdx.x];
}

// =======================================================================
// K5: attention apply (bf16 Q) -> bf16 msg
// =======================================================================
__global__ __launch_bounds__(256) void attn_apply_k(
    const u16* __restrict__ Q, const float* __restrict__ KV,
    u16* __restrict__ outp)
{
    __shared__ float kvs[8192];
    __shared__ float kss[256];
    __shared__ float qs[8][256];

    const int t0 = blockIdx.x * 64;
    const int batch = t0 / LB;
    const float* kvb = KV + (size_t)batch * KVSZ;
    for (int i = threadIdx.x; i < 8192; i += 256) kvs[i] = kvb[i];
    kss[threadIdx.x] = kvb[8192 + threadIdx.x];
    const int h = threadIdx.x >> 5, e = threadIdx.x & 31;
    __syncthreads();

    for (int o = 0; o < 64; o += 8) {
        __syncthreads();
        for (int i = 0; i < 8; ++i)
            qs[i][threadIdx.x] = bf2f(Q[(size_t)(t0 + o + i) * 256 + threadIdx.x]);
        __syncthreads();
        for (int tt = 0; tt < 8; ++tt) {
            const float* qh = &qs[tt][h << 5];
            float zq = 0.f, res = 0.f;
#pragma unroll
            for (int d = 0; d < 32; ++d) {
                const float qd = qh[d];
                zq  += qd * kss[(h << 5) + d];
                res += qd * kvs[((h << 5) + d) * 32 + e];
            }
            outp[(size_t)(t0 + o + tt) * 256 + threadIdx.x] = f2bf(res / (zq + 1e-6f));
        }
    }
}

// =======================================================================
// K7: combined = x + scatter(outsel) fused with window_reverse -> NCHW
// =======================================================================
__global__ __launch_bounds__(256) void combine_reverse_k(
    const float* __restrict__ xin, const int* __restrict__ idxX,
    const u16* __restrict__ outsel, float* __restrict__ outp)
{
    __shared__ float tile[128 * 33];
    __shared__ int   sidx[32];

    const int p  = blockIdx.x;
    const int c0 = blockIdx.y * 32;
    const int b  = p / 1152;
    const int rem = p % 1152;
    const int wy  = rem / 24, wxp = rem % 24;
    const int w0  = b * NWIN + wy * 48 + wxp * 2;
    const int tid = threadIdx.x;

    if (tid < 32) sidx[tid] = idxX[(w0 + (tid >> 4)) * TOPK_ + (tid & 15)];

    {
        const int r = tid >> 1, half = tid & 1;
        const int wl = r >> 6, t = r & 63;
        const float* srcp = xin + ((size_t)(w0 + wl) * 64 + t) * 256 + c0 + half * 16;
        const float4 v0 = ((const float4*)srcp)[0];
        const float4 v1 = ((const float4*)srcp)[1];
        const float4 v2 = ((const float4*)srcp)[2];
        const float4 v3 = ((const float4*)srcp)[3];
        float* dst = &tile[r * 33 + half * 16];
        dst[0] = v0.x; dst[1] = v0.y; dst[2]  = v0.z; dst[3]  = v0.w;
        dst[4] = v1.x; dst[5] = v1.y; dst[6]  = v1.z; dst[7]  = v1.w;
        dst[8] = v2.x; dst[9] = v2.y; dst[10] = v2.z; dst[11] = v2.w;
        dst[12] = v3.x; dst[13] = v3.y; dst[14] = v3.z; dst[15] = v3.w;
    }
    __syncthreads();

    for (int it = 0; it < 4; ++it) {
        const int rid = it * 8 + (tid >> 5);
        const int cc  = tid & 31;
        const int wl  = rid >> 4, j = rid & 15;
        const int t   = sidx[rid];
        tile[((wl << 6) + t) * 33 + cc] +=
            bf2f(outsel[((size_t)(w0 + wl) * TOPK_ + j) * 256 + c0 + cc]);
    }
    __syncthreads();

    const int chalf = tid >> 7;
    const int pix = tid & 127;
    const int dy = pix >> 4, x16 = pix & 15;
    const int wl = x16 >> 3, dx = x16 & 7;
    const int rr = (wl << 6) + dy * 8 + dx;
    const size_t obase = (((size_t)b * 256 + c0 + chalf) * HW + (wy * 8 + dy)) * HW
                       + wxp * 16 + x16;
    for (int cc = 0; cc < 32; cc += 2)
        outp[obase + (size_t)cc * (HW * HW)] = tile[rr * 33 + cc + chalf];
}

// =======================================================================
extern "C" void kernel_launch(void* const* d_in, const int* in_sizes, int n_in,
                              void* d_out, int out_size, void* d_ws, size_t ws_size,
                              hipStream_t stream)
{
    const float* x   = (const float*)d_in[0];
    const float* s   = (const float*)d_in[1];
    const float* Wq  = (const float*)d_in[2];
    const float* Wk  = (const float*)d_in[3];
    const float* Wv  = (const float*)d_in[4];
    const float* Wm  = (const float*)d_in[5];
    const float* W1  = (const float*)d_in[6];
    const float* W2  = (const float*)d_in[7];
    const float* n1w = (const float*)d_in[8];
    const float* n1b = (const float*)d_in[9];
    const float* n2w = (const float*)d_in[10];
    const float* n2b = (const float*)d_in[11];
    float* out = (float*)d_out;

    // ---- workspace layout (bytes) ----
    char* ws = (char*)d_ws;
    int*   idxX   = (int*)ws;                          //    294,912
    float* KVpart = (float*)(ws + 294912);             // 25,952,256
    float* KVfin  = (float*)(ws + 26247168);           //     67,584
    u16*   Wqt    = (u16*)(ws + 26314752);             //    131,072
    u16*   Wkt    = (u16*)(ws + 26445824);             //    131,072
    u16*   Wvt    = (u16*)(ws + 26576896);             //    131,072
    u16*   Wmt    = (u16*)(ws + 26707968);             //    131,072
    u16*   W1t    = (u16*)(ws + 26839040);             //    524,288
    u16*   W2t    = (u16*)(ws + 27363328);             //    262,144
    u16*   Qb     = (u16*)(ws + 27625472);             // 37,748,736
    u16*   Kb     = (u16*)(ws + 65374208);             // 37,748,736
    u16*   Vb     = (u16*)(ws + 103122944);            // 37,748,736
    u16*   osel   = (u16*)(ws + 140871680);            // 37,748,736  outsel (bf16)

    // ---- bf16 intermediates in d_out (dead before final combine) ----
    u16* catA  = (u16*)d_out;                          // [T][512] sel1 | LN1(merge)
    u16* selSb = (u16*)((char*)d_out + 75497472);      // [T][256]
    u16* msgA  = (u16*)((char*)d_out + 113246208);     // [T][256]
    u16* Hb    = (u16*)((char*)d_out + 150994944);     // [T][512]

    // 0) weights -> bf16 transposed [N][K]
    wconv_all_k<<<dim3(2560), 256, 0, stream>>>(Wq, Wk, Wv, Wm, W1, W2,
                                                Wqt, Wkt, Wvt, Wmt, W1t, W2t);

    // 1) top-k + gather
    topk_gather_k<<<dim3(BN, 2), 512, 0, stream>>>(x, s, catA, selSb, idxX);

    // 2) fused Q/K/V GEMMs (128x256 tiles, bf16 out)
    gemm_qkv_k<<<dim3(1, 576, 3), 512, 0, stream>>>(catA, selSb, Wqt, Wkt, Wvt,
                                                    Qb, Kb, Vb);

    // 3) KV / Ksum aggregation (deterministic two-stage)
    kv_part_k<<<dim3(2 * KVB), 256, 0, stream>>>(Kb, Vb, KVpart);
    kv_reduce_k<<<dim3(2 * (KVSZ / 64)), 256, 0, stream>>>(KVpart, KVfin);

    // 4) attention apply -> bf16 msg
    attn_apply_k<<<dim3(TROWS / 64), 256, 0, stream>>>(Qb, KVfin, msgA);

    // 5) merge GEMM + fused LN1 -> catA right half (bf16)
    gemm8_k<0, 1><<<dim3(1, 576), 512, 0, stream>>>(
        msgA, 256, Wmt, 256, catA + 256, 512, n1w, n1b, nullptr, nullptr);

    // 6) H = relu(cat@W1) (bf16, 128x256 tiles)
    gemm8_k<2, 0><<<dim3(2, 576), 512, 0, stream>>>(
        catA, 512, W1t, 512, Hb, 512, nullptr, nullptr, nullptr, nullptr);

    // 7) W2 GEMM + fused LN2 + residual gather -> osel (bf16)
    gemm8_k<0, 2><<<dim3(1, 576), 512, 0, stream>>>(
        Hb, 512, W2t, 512, osel, 256, n2w, n2b, x, idxX);

    // 8) combined = x + scatter(outsel); window_reverse -> NCHW out
    combine_reverse_k<<<dim3(BN / 2, 8), 256, 0, stream>>>(x, idxX, osel, out);
}